// Round 9
// baseline (474.900 us; speedup 1.0000x reference)
//
#include <hip/hip_runtime.h>

#define NPTS 120000
#define NROW 120064   // padded row count (multiple of 256)
#define NB   60000
#define TAPS 27
#define NBLK (NROW / 128)   // 938 conv blocks

typedef short  short8 __attribute__((ext_vector_type(8)));
typedef float  f32x4  __attribute__((ext_vector_type(4)));
typedef unsigned int u32;

__device__ __forceinline__ float bf2f(unsigned short u) {
  unsigned v = ((unsigned)u) << 16;
  float f; __builtin_memcpy(&f, &v, 4); return f;
}
__device__ __forceinline__ unsigned short f2bf(float f) {
  unsigned v; __builtin_memcpy(&v, &f, 4);
  v = v + 0x7FFFu + ((v >> 16) & 1u);   // RNE (finite values only)
  return (unsigned short)(v >> 16);
}

// bijective chunked XCD swizzle (m204): blocks with orig%8==x get a contiguous chunk
__device__ __forceinline__ int xcd_swz(int orig, int nwg) {
  int q = nwg >> 3, r = nwg & 7;
  int x = orig & 7, i = orig >> 3;
  return (x < r ? x * (q + 1) : r * (q + 1) + (x - r) * q) + i;
}

// ---- fused init: nbr=-1, weight repack, SM zeros ----
__global__ __launch_bounds__(256) void k_init(int* __restrict__ nbr,
                                              const float* __restrict__ w,
                                              unsigned short* __restrict__ wp,
                                              float* __restrict__ SMa) {
  int b = blockIdx.x, t = threadIdx.x;
  if (b < 12663) {                       // TAPS*NROW/256 == 12663
    nbr[b * 256 + t] = -1;
    return;
  }
  b -= 12663;
  if (b < 1728) {                        // repack 108*4096 bf16 B-fragments
    int g = b * 256 + t;
    int e = g & 7, l = (g >> 3) & 63, f = (g >> 9) & 7, rest = g >> 12;
    int tt = f >> 1, h = f & 1;
    int kk = h * 32 + (l >> 4) * 8 + e;
    int cc = tt * 16 + (l & 15);
    wp[g] = f2bf(w[(rest * 64 + kk) * 64 + cc]);
    return;
  }
  if (t < 1280) SMa[t] = 0.f;            // SM0..SM4
}

// ---- invert kernel map: nbr[k*NROW + out_row] = in_row ----
__global__ __launch_bounds__(256) void k_build_nbr(const int* __restrict__ oi,
                                                   const int* __restrict__ ii,
                                                   int* __restrict__ nbr) {
  int g = blockIdx.x * 256 + threadIdx.x;
  if (g >= TAPS * NPTS) return;
  int o = oi[g];
  if (o < NPTS) nbr[(g / NPTS) * NROW + o] = ii[g];
}

// ---- stats pass 1 (f32 input, first IN): atomic partials into SM[bs*64+c] ----
__global__ __launch_bounds__(256) void k_stats1_f32(const float* __restrict__ F,
                                                    float* __restrict__ SM) {
  int lane = threadIdx.x & 63, wave = threadIdx.x >> 6;
  int batch = blockIdx.x >> 7, bb = blockIdx.x & 127;
  const float* Fb = F + (size_t)batch * NB * 64;
  float s = 0.f, ss = 0.f;
  for (int r = bb * 4 + wave; r < NB; r += 512) {
    float v = Fb[(size_t)r * 64 + lane];
    s += v; ss += v * v;
  }
  __shared__ float ls[4][64], lss[4][64];
  ls[wave][lane] = s; lss[wave][lane] = ss;
  __syncthreads();
  if (threadIdx.x < 64) {
    float S  = ls[0][lane] + ls[1][lane] + ls[2][lane] + ls[3][lane];
    float SS = lss[0][lane] + lss[1][lane] + lss[2][lane] + lss[3][lane];
    atomicAdd(&SM[(batch * 2 + 0) * 64 + lane], S);
    atomicAdd(&SM[(batch * 2 + 1) * 64 + lane], SS);
  }
}

// ---- first apply: f32 feats -> bf16 X, relu(norm), stats inline from SM ----
__global__ __launch_bounds__(256) void k_apply_f2b(const float* __restrict__ F,
                                                   const float* __restrict__ SM,
                                                   unsigned short* __restrict__ O) {
  int i = blockIdx.x * 256 + threadIdx.x;          // 960000 groups of 8
  int r = i >> 3, cb = (i & 7) * 8;
  int b = (r >= NB) ? 1 : 0;
  f32x4 v0 = *((const f32x4*)F + i * 2);
  f32x4 v1 = *((const f32x4*)F + i * 2 + 1);
  short8 o;
#pragma unroll
  for (int e = 0; e < 8; ++e) {
    float mean = SM[(b * 2 + 0) * 64 + cb + e] * (1.f / NB);
    float var  = SM[(b * 2 + 1) * 64 + cb + e] * (1.f / NB) - mean * mean;
    float rstd = rsqrtf(var + 1e-5f);
    float x = (e < 4) ? v0[e & 3] : v1[e & 3];
    o[e] = (short)f2bf(fmaxf((x - mean) * rstd, 0.f));
  }
  *((short8*)O + i) = o;
}

// ---- O = relu(norm(F)), bf16 -> bf16, stats inline ----
__global__ __launch_bounds__(256) void k_apply_bf(const unsigned short* __restrict__ F,
                                                  const float* __restrict__ SM,
                                                  unsigned short* __restrict__ O) {
  int i = blockIdx.x * 256 + threadIdx.x;
  int r = i >> 3, cb = (i & 7) * 8;
  int b = (r >= NB) ? 1 : 0;
  short8 v = *((const short8*)F + i);
  short8 o;
#pragma unroll
  for (int e = 0; e < 8; ++e) {
    float mean = SM[(b * 2 + 0) * 64 + cb + e] * (1.f / NB);
    float var  = SM[(b * 2 + 1) * 64 + cb + e] * (1.f / NB) - mean * mean;
    float rstd = rsqrtf(var + 1e-5f);
    float f = (bf2f((unsigned short)v[e]) - mean) * rstd;
    o[e] = (short)f2bf(fmaxf(f, 0.f));
  }
  *((short8*)O + i) = o;
}

// ---- X = relu(norm(H2) + X), bf16, stats inline ----
__global__ __launch_bounds__(256) void k_apply_res_bf(const unsigned short* __restrict__ H2,
                                                      const float* __restrict__ SM,
                                                      unsigned short* __restrict__ X) {
  int i = blockIdx.x * 256 + threadIdx.x;
  int r = i >> 3, cb = (i & 7) * 8;
  int b = (r >= NB) ? 1 : 0;
  short8 v = *((const short8*)H2 + i);
  short8 xv = *((const short8*)X + i);
  short8 o;
#pragma unroll
  for (int e = 0; e < 8; ++e) {
    float mean = SM[(b * 2 + 0) * 64 + cb + e] * (1.f / NB);
    float var  = SM[(b * 2 + 1) * 64 + cb + e] * (1.f / NB) - mean * mean;
    float rstd = rsqrtf(var + 1e-5f);
    float f = (bf2f((unsigned short)v[e]) - mean) * rstd + bf2f((unsigned short)xv[e]);
    o[e] = (short)f2bf(fmaxf(f, 0.f));
  }
  *((short8*)X + i) = o;
}

// ---- gather-MFMA sparse conv 64->64, 32 rows/wave, XCD-swizzled, fused stats ----
__global__ __launch_bounds__(256) void k_conv64s(const unsigned short* __restrict__ X,
                                                 const unsigned short* __restrict__ WP,
                                                 const int* __restrict__ nbr,
                                                 unsigned short* __restrict__ Y,
                                                 float* __restrict__ SM) {
  const int blk = xcd_swz(blockIdx.x, NBLK);
  const int lane = threadIdx.x & 63, wave = threadIdx.x >> 6;
  const int j0w = blk * 128 + wave * 32;
  const int lrow = lane & 15, lk = lane >> 4;
  f32x4 acc[2][4];
#pragma unroll
  for (int g = 0; g < 2; ++g)
#pragma unroll
    for (int c = 0; c < 4; ++c) acc[g][c] = (f32x4){0.f, 0.f, 0.f, 0.f};

  for (int k = 0; k < TAPS; ++k) {
    const int* np = nbr + (size_t)k * NROW + j0w + lrow;
    int i0 = np[0], i1 = np[16];
    if (__ballot(i0 >= 0 || i1 >= 0) == 0ull) continue;
    short8 a00 = {0,0,0,0,0,0,0,0}, a01 = {0,0,0,0,0,0,0,0};
    short8 a10 = {0,0,0,0,0,0,0,0}, a11 = {0,0,0,0,0,0,0,0};
    if (i0 >= 0) {
      const unsigned short* rp = X + (size_t)i0 * 64 + lk * 8;
      a00 = *(const short8*)rp; a01 = *(const short8*)(rp + 32);
    }
    if (i1 >= 0) {
      const unsigned short* rp = X + (size_t)i1 * 64 + lk * 8;
      a10 = *(const short8*)rp; a11 = *(const short8*)(rp + 32);
    }
    const unsigned short* wpk = WP + k * 4096 + lane * 8;
#pragma unroll
    for (int ct = 0; ct < 4; ++ct) {
      short8 b0 = *(const short8*)(wpk + ct * 1024);
      short8 b1 = *(const short8*)(wpk + ct * 1024 + 512);
      acc[0][ct] = __builtin_amdgcn_mfma_f32_16x16x32_bf16(a00, b0, acc[0][ct], 0, 0, 0);
      acc[0][ct] = __builtin_amdgcn_mfma_f32_16x16x32_bf16(a01, b1, acc[0][ct], 0, 0, 0);
      acc[1][ct] = __builtin_amdgcn_mfma_f32_16x16x32_bf16(a10, b0, acc[1][ct], 0, 0, 0);
      acc[1][ct] = __builtin_amdgcn_mfma_f32_16x16x32_bf16(a11, b1, acc[1][ct], 0, 0, 0);
    }
  }

  // C/D: col = lane&15 (+ct*16), row = (lane>>4)*4 + reg (+g*16)
#pragma unroll
  for (int g = 0; g < 2; ++g) {
    unsigned short* yp = Y + (size_t)(j0w + g * 16 + lk * 4) * 64 + lrow;
#pragma unroll
    for (int r = 0; r < 4; ++r) {
      yp[r * 64 +  0] = f2bf(acc[g][0][r]);
      yp[r * 64 + 16] = f2bf(acc[g][1][r]);
      yp[r * 64 + 32] = f2bf(acc[g][2][r]);
      yp[r * 64 + 48] = f2bf(acc[g][3][r]);
    }
  }

  // fused IN stats: per-lane sum/sumsq over its 8 rows, batch-split
  float s[4][2], q[4][2];
#pragma unroll
  for (int ct = 0; ct < 4; ++ct) { s[ct][0] = s[ct][1] = q[ct][0] = q[ct][1] = 0.f; }
#pragma unroll
  for (int g = 0; g < 2; ++g) {
    int rowbase = j0w + g * 16 + lk * 4;
#pragma unroll
    for (int r = 0; r < 4; ++r) {
      int bt = (rowbase + r) >= NB;
#pragma unroll
      for (int ct = 0; ct < 4; ++ct) {
        float v = acc[g][ct][r];
        s[ct][bt] += v; q[ct][bt] += v * v;
      }
    }
  }
  __shared__ float sred[4][4][4][64];   // [wave][lk][batch*2+stat][col]
#pragma unroll
  for (int ct = 0; ct < 4; ++ct)
#pragma unroll
    for (int b = 0; b < 2; ++b) {
      sred[wave][lk][b * 2 + 0][ct * 16 + lrow] = s[ct][b];
      sred[wave][lk][b * 2 + 1][ct * 16 + lrow] = q[ct][b];
    }
  __syncthreads();
  int t = threadIdx.x;
  float S = 0.f;
#pragma unroll
  for (int w = 0; w < 4; ++w)
#pragma unroll
    for (int l2 = 0; l2 < 4; ++l2)
      S += sred[w][l2][t >> 6][t & 63];
  atomicAdd(&SM[t], S);
}

// ---- final stage 1: D[k][i] = X[i] . WF[k]  (MFMA GEMM 120064x64 @ 64x27) ----
__global__ __launch_bounds__(256) void k_dfin(const unsigned short* __restrict__ X,
                                              const float* __restrict__ WF,
                                              float* __restrict__ D) {
  const int lane = threadIdx.x & 63, wave = threadIdx.x >> 6;
  const int j0 = blockIdx.x * 64 + wave * 16;
  const int lrow = lane & 15, lk = lane >> 4;
  const unsigned short* rp = X + (size_t)(j0 + lrow) * 64 + lk * 8;
  short8 a0 = *(const short8*)rp;
  short8 a1 = *(const short8*)(rp + 32);
  short8 b[2][2];
#pragma unroll
  for (int ct = 0; ct < 2; ++ct) {
    int col = ct * 16 + lrow;
#pragma unroll
    for (int h = 0; h < 2; ++h) {
#pragma unroll
      for (int e = 0; e < 8; ++e)
        b[ct][h][e] = (col < TAPS) ? (short)f2bf(WF[col * 64 + h * 32 + lk * 8 + e]) : (short)0;
    }
  }
  f32x4 acc0 = {0,0,0,0}, acc1 = {0,0,0,0};
  acc0 = __builtin_amdgcn_mfma_f32_16x16x32_bf16(a0, b[0][0], acc0, 0, 0, 0);
  acc0 = __builtin_amdgcn_mfma_f32_16x16x32_bf16(a1, b[0][1], acc0, 0, 0, 0);
  acc1 = __builtin_amdgcn_mfma_f32_16x16x32_bf16(a0, b[1][0], acc1, 0, 0, 0);
  acc1 = __builtin_amdgcn_mfma_f32_16x16x32_bf16(a1, b[1][1], acc1, 0, 0, 0);
  float* dp0 = D + (size_t)lrow * NROW + j0 + lk * 4;
  float* dp1 = D + (size_t)(16 + lrow) * NROW + j0 + lk * 4;
#pragma unroll
  for (int r = 0; r < 4; ++r) { dp0[r] = acc0[r]; dp1[r] = acc1[r]; }
}

// ---- final stage 2: out[j] = bias + sum_k D[k][nbr[k][j]], XCD-swizzled ----
__global__ __launch_bounds__(256) void k_gfin(const float* __restrict__ D,
                                              const int* __restrict__ nbr,
                                              const float* __restrict__ BF,
                                              float* __restrict__ out) {
  int j = xcd_swz(blockIdx.x, NROW / 256) * 256 + threadIdx.x;
  if (j >= NPTS) return;
  float acc = BF[0];
#pragma unroll
  for (int k = 0; k < TAPS; ++k) {
    int idx = nbr[(size_t)k * NROW + j];
    if (idx >= 0) acc += D[(size_t)k * NROW + idx];
  }
  out[j] = acc;
}

extern "C" void kernel_launch(void* const* d_in, const int* in_sizes, int n_in,
                              void* d_out, int out_size, void* d_ws, size_t ws_size,
                              hipStream_t stream) {
  (void)in_sizes; (void)n_in; (void)out_size; (void)ws_size;
  const float* feats = (const float*)d_in[0];
  const float* wblk  = (const float*)d_in[1];
  const float* wfin  = (const float*)d_in[2];
  const float* bfin  = (const float*)d_in[3];
  const int* in_idx  = (const int*)d_in[4];
  const int* out_idx = (const int*)d_in[5];

  char* p = (char*)d_ws;
  size_t off = 0;
  auto carve = [&](size_t bytes) {
    void* r = p + off; off += (bytes + 255) & ~(size_t)255; return r;
  };
  int*            nbr = (int*)carve((size_t)TAPS * NROW * 4);               // 12.97 MB
  unsigned short* Xb  = (unsigned short*)carve((size_t)NROW * 64 * 2);      // 15.37 MB
  unsigned short* Hb  = (unsigned short*)carve((size_t)NROW * 64 * 2);
  unsigned short* H2b = (unsigned short*)carve((size_t)NROW * 64 * 2);
  unsigned short* WP  = (unsigned short*)carve(108u * 4096u * 2);           // 0.88 MB
  float*          D   = (float*)carve((size_t)32 * NROW * 4);               // 15.4 MB
  float*          SMa = (float*)carve(5 * 256 * 4);                         // SM0..SM4

  float* SM0 = SMa;
  float* SM1 = SMa + 256;
  float* SM2 = SMa + 512;
  float* SM3 = SMa + 768;
  float* SM4 = SMa + 1024;

  k_init<<<12663 + 1728 + 1, 256, 0, stream>>>(nbr, wblk, WP, SMa);
  k_build_nbr<<<(TAPS * NPTS + 255) / 256, 256, 0, stream>>>(out_idx, in_idx, nbr);

  // x = relu(IN(feats))
  k_stats1_f32<<<256, 256, 0, stream>>>(feats, SM0);
  k_apply_f2b<<<3750, 256, 0, stream>>>(feats, SM0, Xb);

  // block 0
  k_conv64s<<<NBLK, 256, 0, stream>>>(Xb, WP + 0 * 110592, nbr, Hb, SM1);
  k_apply_bf<<<3750, 256, 0, stream>>>(Hb, SM1, Hb);
  k_conv64s<<<NBLK, 256, 0, stream>>>(Hb, WP + 1 * 110592, nbr, H2b, SM2);
  k_apply_res_bf<<<3750, 256, 0, stream>>>(H2b, SM2, Xb);

  // block 1
  k_conv64s<<<NBLK, 256, 0, stream>>>(Xb, WP + 2 * 110592, nbr, Hb, SM3);
  k_apply_bf<<<3750, 256, 0, stream>>>(Hb, SM3, Hb);
  k_conv64s<<<NBLK, 256, 0, stream>>>(Hb, WP + 3 * 110592, nbr, H2b, SM4);
  k_apply_res_bf<<<3750, 256, 0, stream>>>(H2b, SM4, Xb);

  // final 64->1 conv + bias: D = X.WF^T then gather-sum
  k_dfin<<<NROW / 64, 256, 0, stream>>>(Xb, wfin, D);
  k_gfin<<<NROW / 256, 256, 0, stream>>>(D, nbr, bfin, (float*)d_out);
}

// Round 10
// 463.301 us; speedup vs baseline: 1.0250x; 1.0250x over previous
//
#include <hip/hip_runtime.h>

#define NPTS 120000
#define NROW 120064   // padded row count (multiple of 256)
#define NB   60000
#define TAPS 27
#define NBLK (NROW / 128)   // 938 conv blocks

typedef short  short8 __attribute__((ext_vector_type(8)));
typedef float  f32x4  __attribute__((ext_vector_type(4)));
typedef int    int4v  __attribute__((ext_vector_type(4)));
typedef unsigned int u32;

__device__ __forceinline__ float bf2f(unsigned short u) {
  unsigned v = ((unsigned)u) << 16;
  float f; __builtin_memcpy(&f, &v, 4); return f;
}
__device__ __forceinline__ unsigned short f2bf(float f) {
  unsigned v; __builtin_memcpy(&v, &f, 4);
  v = v + 0x7FFFu + ((v >> 16) & 1u);   // RNE (finite values only)
  return (unsigned short)(v >> 16);
}

// normalize 8 raw bf16 values with per-channel A=rstd, B=-mean*rstd, relu, repack bf16
__device__ __forceinline__ short8 norm8(short8 v, const float* A, const float* B) {
  float f[8];
#pragma unroll
  for (int e = 0; e < 8; ++e)
    f[e] = fmaxf(fmaf(bf2f((unsigned short)v[e]), A[e], B[e]), 0.f);
  int4v p;
#pragma unroll
  for (int j = 0; j < 4; ++j) {
    u32 r;
    asm("v_cvt_pk_bf16_f32 %0, %1, %2" : "=v"(r) : "v"(f[2 * j]), "v"(f[2 * j + 1]));
    p[j] = (int)r;
  }
  union { int4v i; short8 s; } u; u.i = p; return u.s;
}

// ---- fused init: nbr=-1, weight repack, SM zeros ----
__global__ __launch_bounds__(256) void k_init(int* __restrict__ nbr,
                                              const float* __restrict__ w,
                                              unsigned short* __restrict__ wp,
                                              float* __restrict__ SMa) {
  int b = blockIdx.x, t = threadIdx.x;
  if (b < 12663) {                       // TAPS*NROW/256 == 12663
    nbr[b * 256 + t] = -1;
    return;
  }
  b -= 12663;
  if (b < 1728) {                        // repack 108*4096 bf16 B-fragments
    int g = b * 256 + t;
    int e = g & 7, l = (g >> 3) & 63, f = (g >> 9) & 7, rest = g >> 12;
    int tt = f >> 1, h = f & 1;
    int kk = h * 32 + (l >> 4) * 8 + e;
    int cc = tt * 16 + (l & 15);
    wp[g] = f2bf(w[(rest * 64 + kk) * 64 + cc]);
    return;
  }
  if (t < 1280) SMa[t] = 0.f;            // SM0..SM4
}

// ---- invert kernel map: nbr[k*NROW + out_row] = in_row ----
__global__ __launch_bounds__(256) void k_build_nbr(const int* __restrict__ oi,
                                                   const int* __restrict__ ii,
                                                   int* __restrict__ nbr) {
  int g = blockIdx.x * 256 + threadIdx.x;
  if (g >= TAPS * NPTS) return;
  int o = oi[g];
  if (o < NPTS) nbr[(g / NPTS) * NROW + o] = ii[g];
}

// ---- stats pass 1 (f32 input, first IN): atomic partials into SM[bs*64+c] ----
__global__ __launch_bounds__(256) void k_stats1_f32(const float* __restrict__ F,
                                                    float* __restrict__ SM) {
  int lane = threadIdx.x & 63, wave = threadIdx.x >> 6;
  int batch = blockIdx.x >> 7, bb = blockIdx.x & 127;
  const float* Fb = F + (size_t)batch * NB * 64;
  float s = 0.f, ss = 0.f;
  for (int r = bb * 4 + wave; r < NB; r += 512) {
    float v = Fb[(size_t)r * 64 + lane];
    s += v; ss += v * v;
  }
  __shared__ float ls[4][64], lss[4][64];
  ls[wave][lane] = s; lss[wave][lane] = ss;
  __syncthreads();
  if (threadIdx.x < 64) {
    float S  = ls[0][lane] + ls[1][lane] + ls[2][lane] + ls[3][lane];
    float SS = lss[0][lane] + lss[1][lane] + lss[2][lane] + lss[3][lane];
    atomicAdd(&SM[(batch * 2 + 0) * 64 + lane], S);
    atomicAdd(&SM[(batch * 2 + 1) * 64 + lane], SS);
  }
}

// ---- first apply: f32 feats -> bf16 X, relu(norm), stats inline from SM ----
__global__ __launch_bounds__(256) void k_apply_f2b(const float* __restrict__ F,
                                                   const float* __restrict__ SM,
                                                   unsigned short* __restrict__ O) {
  int i = blockIdx.x * 256 + threadIdx.x;          // 960000 groups of 8
  int r = i >> 3, cb = (i & 7) * 8;
  int b = (r >= NB) ? 1 : 0;
  f32x4 v0 = *((const f32x4*)F + i * 2);
  f32x4 v1 = *((const f32x4*)F + i * 2 + 1);
  short8 o;
#pragma unroll
  for (int e = 0; e < 8; ++e) {
    float mean = SM[(b * 2 + 0) * 64 + cb + e] * (1.f / NB);
    float var  = SM[(b * 2 + 1) * 64 + cb + e] * (1.f / NB) - mean * mean;
    float rstd = rsqrtf(var + 1e-5f);
    float x = (e < 4) ? v0[e & 3] : v1[e & 3];
    o[e] = (short)f2bf(fmaxf((x - mean) * rstd, 0.f));
  }
  *((short8*)O + i) = o;
}

// ---- X = relu(norm(H2) + X), bf16, stats inline ----
__global__ __launch_bounds__(256) void k_apply_res_bf(const unsigned short* __restrict__ H2,
                                                      const float* __restrict__ SM,
                                                      unsigned short* __restrict__ X) {
  int i = blockIdx.x * 256 + threadIdx.x;
  int r = i >> 3, cb = (i & 7) * 8;
  int b = (r >= NB) ? 1 : 0;
  short8 v = *((const short8*)H2 + i);
  short8 xv = *((const short8*)X + i);
  short8 o;
#pragma unroll
  for (int e = 0; e < 8; ++e) {
    float mean = SM[(b * 2 + 0) * 64 + cb + e] * (1.f / NB);
    float var  = SM[(b * 2 + 1) * 64 + cb + e] * (1.f / NB) - mean * mean;
    float rstd = rsqrtf(var + 1e-5f);
    float f = (bf2f((unsigned short)v[e]) - mean) * rstd + bf2f((unsigned short)xv[e]);
    o[e] = (short)f2bf(fmaxf(f, 0.f));
  }
  *((short8*)X + i) = o;
}

// ---- gather-MFMA sparse conv 64->64, 32 rows/wave, idx prefetch, fused stats.
//      NORM=0: input already normalized. NORM=1: normalize gathers from SMin. ----
template <int NORM>
__global__ __launch_bounds__(256) void k_conv64t(const unsigned short* __restrict__ X,
                                                 const unsigned short* __restrict__ WP,
                                                 const int* __restrict__ nbr,
                                                 unsigned short* __restrict__ Y,
                                                 const float* __restrict__ SMin,
                                                 float* __restrict__ SM) {
  const int lane = threadIdx.x & 63, wave = threadIdx.x >> 6;
  const int j0w = blockIdx.x * 128 + wave * 32;
  const int lrow = lane & 15, lk = lane >> 4;

  float A0[8], B0[8], A1[8], B1[8];
  if (NORM) {
    int batch = (j0w >= NB) ? 1 : 0;     // waves never straddle NB (NB%32==0)
    const float* S0 = SMin + (batch * 2 + 0) * 64;
    const float* S1 = SMin + (batch * 2 + 1) * 64;
#pragma unroll
    for (int e = 0; e < 8; ++e) {
      int c0 = lk * 8 + e, c1 = 32 + lk * 8 + e;
      float m0 = S0[c0] * (1.f / NB);
      float r0 = rsqrtf(S1[c0] * (1.f / NB) - m0 * m0 + 1e-5f);
      A0[e] = r0; B0[e] = -m0 * r0;
      float m1 = S0[c1] * (1.f / NB);
      float r1 = rsqrtf(S1[c1] * (1.f / NB) - m1 * m1 + 1e-5f);
      A1[e] = r1; B1[e] = -m1 * r1;
    }
  }

  f32x4 acc[2][4];
#pragma unroll
  for (int g = 0; g < 2; ++g)
#pragma unroll
    for (int c = 0; c < 4; ++c) acc[g][c] = (f32x4){0.f, 0.f, 0.f, 0.f};

  const int* np = nbr + j0w + lrow;
  int i0 = np[0], i1 = np[16];
  for (int k = 0; k < TAPS; ++k) {
    int ni0 = 0, ni1 = 0;
    if (k + 1 < TAPS) {                   // prefetch next tap's indices early
      const int* npn = np + (size_t)(k + 1) * NROW;
      ni0 = npn[0]; ni1 = npn[16];
    }
    if (__ballot(i0 >= 0 || i1 >= 0) != 0ull) {
      short8 a00 = {0,0,0,0,0,0,0,0}, a01 = {0,0,0,0,0,0,0,0};
      short8 a10 = {0,0,0,0,0,0,0,0}, a11 = {0,0,0,0,0,0,0,0};
      if (i0 >= 0) {
        const unsigned short* rp = X + (size_t)i0 * 64 + lk * 8;
        a00 = *(const short8*)rp; a01 = *(const short8*)(rp + 32);
        if (NORM) { a00 = norm8(a00, A0, B0); a01 = norm8(a01, A1, B1); }
      }
      if (i1 >= 0) {
        const unsigned short* rp = X + (size_t)i1 * 64 + lk * 8;
        a10 = *(const short8*)rp; a11 = *(const short8*)(rp + 32);
        if (NORM) { a10 = norm8(a10, A0, B0); a11 = norm8(a11, A1, B1); }
      }
      const unsigned short* wpk = WP + k * 4096 + lane * 8;
#pragma unroll
      for (int ct = 0; ct < 4; ++ct) {
        short8 b0 = *(const short8*)(wpk + ct * 1024);
        short8 b1 = *(const short8*)(wpk + ct * 1024 + 512);
        acc[0][ct] = __builtin_amdgcn_mfma_f32_16x16x32_bf16(a00, b0, acc[0][ct], 0, 0, 0);
        acc[0][ct] = __builtin_amdgcn_mfma_f32_16x16x32_bf16(a01, b1, acc[0][ct], 0, 0, 0);
        acc[1][ct] = __builtin_amdgcn_mfma_f32_16x16x32_bf16(a10, b0, acc[1][ct], 0, 0, 0);
        acc[1][ct] = __builtin_amdgcn_mfma_f32_16x16x32_bf16(a11, b1, acc[1][ct], 0, 0, 0);
      }
    }
    i0 = ni0; i1 = ni1;
  }

  // C/D: col = lane&15 (+ct*16), row = (lane>>4)*4 + reg (+g*16)
#pragma unroll
  for (int g = 0; g < 2; ++g) {
    unsigned short* yp = Y + (size_t)(j0w + g * 16 + lk * 4) * 64 + lrow;
#pragma unroll
    for (int r = 0; r < 4; ++r) {
      yp[r * 64 +  0] = f2bf(acc[g][0][r]);
      yp[r * 64 + 16] = f2bf(acc[g][1][r]);
      yp[r * 64 + 32] = f2bf(acc[g][2][r]);
      yp[r * 64 + 48] = f2bf(acc[g][3][r]);
    }
  }

  // fused IN stats of raw conv output: per-lane sum/sumsq, batch-split
  float s[4][2], q[4][2];
#pragma unroll
  for (int ct = 0; ct < 4; ++ct) { s[ct][0] = s[ct][1] = q[ct][0] = q[ct][1] = 0.f; }
#pragma unroll
  for (int g = 0; g < 2; ++g) {
    int rowbase = j0w + g * 16 + lk * 4;
#pragma unroll
    for (int r = 0; r < 4; ++r) {
      int bt = (rowbase + r) >= NB;
#pragma unroll
      for (int ct = 0; ct < 4; ++ct) {
        float v = acc[g][ct][r];
        s[ct][bt] += v; q[ct][bt] += v * v;
      }
    }
  }
  __shared__ float sred[4][4][4][64];   // [wave][lk][batch*2+stat][col]
#pragma unroll
  for (int ct = 0; ct < 4; ++ct)
#pragma unroll
    for (int b = 0; b < 2; ++b) {
      sred[wave][lk][b * 2 + 0][ct * 16 + lrow] = s[ct][b];
      sred[wave][lk][b * 2 + 1][ct * 16 + lrow] = q[ct][b];
    }
  __syncthreads();
  int t = threadIdx.x;
  float S = 0.f;
#pragma unroll
  for (int w = 0; w < 4; ++w)
#pragma unroll
    for (int l2 = 0; l2 < 4; ++l2)
      S += sred[w][l2][t >> 6][t & 63];
  atomicAdd(&SM[t], S);
}

// ---- final stage 1: D[k][i] = X[i] . WF[k]  (MFMA GEMM 120064x64 @ 64x27) ----
__global__ __launch_bounds__(256) void k_dfin(const unsigned short* __restrict__ X,
                                              const float* __restrict__ WF,
                                              float* __restrict__ D) {
  const int lane = threadIdx.x & 63, wave = threadIdx.x >> 6;
  const int j0 = blockIdx.x * 64 + wave * 16;
  const int lrow = lane & 15, lk = lane >> 4;
  const unsigned short* rp = X + (size_t)(j0 + lrow) * 64 + lk * 8;
  short8 a0 = *(const short8*)rp;
  short8 a1 = *(const short8*)(rp + 32);
  short8 b[2][2];
#pragma unroll
  for (int ct = 0; ct < 2; ++ct) {
    int col = ct * 16 + lrow;
#pragma unroll
    for (int h = 0; h < 2; ++h) {
#pragma unroll
      for (int e = 0; e < 8; ++e)
        b[ct][h][e] = (col < TAPS) ? (short)f2bf(WF[col * 64 + h * 32 + lk * 8 + e]) : (short)0;
    }
  }
  f32x4 acc0 = {0,0,0,0}, acc1 = {0,0,0,0};
  acc0 = __builtin_amdgcn_mfma_f32_16x16x32_bf16(a0, b[0][0], acc0, 0, 0, 0);
  acc0 = __builtin_amdgcn_mfma_f32_16x16x32_bf16(a1, b[0][1], acc0, 0, 0, 0);
  acc1 = __builtin_amdgcn_mfma_f32_16x16x32_bf16(a0, b[1][0], acc1, 0, 0, 0);
  acc1 = __builtin_amdgcn_mfma_f32_16x16x32_bf16(a1, b[1][1], acc1, 0, 0, 0);
  float* dp0 = D + (size_t)lrow * NROW + j0 + lk * 4;
  float* dp1 = D + (size_t)(16 + lrow) * NROW + j0 + lk * 4;
#pragma unroll
  for (int r = 0; r < 4; ++r) { dp0[r] = acc0[r]; dp1[r] = acc1[r]; }
}

// ---- final stage 2: out[j] = bias + sum_k D[k][nbr[k][j]] ----
__global__ __launch_bounds__(256) void k_gfin(const float* __restrict__ D,
                                              const int* __restrict__ nbr,
                                              const float* __restrict__ BF,
                                              float* __restrict__ out) {
  int j = blockIdx.x * 256 + threadIdx.x;
  if (j >= NPTS) return;
  float acc = BF[0];
#pragma unroll
  for (int k = 0; k < TAPS; ++k) {
    int idx = nbr[(size_t)k * NROW + j];
    if (idx >= 0) acc += D[(size_t)k * NROW + idx];
  }
  out[j] = acc;
}

extern "C" void kernel_launch(void* const* d_in, const int* in_sizes, int n_in,
                              void* d_out, int out_size, void* d_ws, size_t ws_size,
                              hipStream_t stream) {
  (void)in_sizes; (void)n_in; (void)out_size; (void)ws_size;
  const float* feats = (const float*)d_in[0];
  const float* wblk  = (const float*)d_in[1];
  const float* wfin  = (const float*)d_in[2];
  const float* bfin  = (const float*)d_in[3];
  const int* in_idx  = (const int*)d_in[4];
  const int* out_idx = (const int*)d_in[5];

  char* p = (char*)d_ws;
  size_t off = 0;
  auto carve = [&](size_t bytes) {
    void* r = p + off; off += (bytes + 255) & ~(size_t)255; return r;
  };
  int*            nbr = (int*)carve((size_t)TAPS * NROW * 4);               // 12.97 MB
  unsigned short* Xb  = (unsigned short*)carve((size_t)NROW * 64 * 2);      // 15.37 MB
  unsigned short* Hb  = (unsigned short*)carve((size_t)NROW * 64 * 2);
  unsigned short* H2b = (unsigned short*)carve((size_t)NROW * 64 * 2);
  unsigned short* WP  = (unsigned short*)carve(108u * 4096u * 2);           // 0.88 MB
  float*          D   = (float*)carve((size_t)32 * NROW * 4);               // 15.4 MB
  float*          SMa = (float*)carve(5 * 256 * 4);                         // SM0..SM4

  float* SM0 = SMa;
  float* SM1 = SMa + 256;
  float* SM2 = SMa + 512;
  float* SM3 = SMa + 768;
  float* SM4 = SMa + 1024;

  k_init<<<12663 + 1728 + 1, 256, 0, stream>>>(nbr, wblk, WP, SMa);
  k_build_nbr<<<(TAPS * NPTS + 255) / 256, 256, 0, stream>>>(out_idx, in_idx, nbr);

  // x = relu(IN(feats))
  k_stats1_f32<<<256, 256, 0, stream>>>(feats, SM0);
  k_apply_f2b<<<3750, 256, 0, stream>>>(feats, SM0, Xb);

  // block 0: conv -> (IN+relu fused into next conv) -> conv -> IN+res+relu
  k_conv64t<0><<<NBLK, 256, 0, stream>>>(Xb, WP + 0 * 110592, nbr, Hb, nullptr, SM1);
  k_conv64t<1><<<NBLK, 256, 0, stream>>>(Hb, WP + 1 * 110592, nbr, H2b, SM1, SM2);
  k_apply_res_bf<<<3750, 256, 0, stream>>>(H2b, SM2, Xb);

  // block 1
  k_conv64t<0><<<NBLK, 256, 0, stream>>>(Xb, WP + 2 * 110592, nbr, Hb, nullptr, SM3);
  k_conv64t<1><<<NBLK, 256, 0, stream>>>(Hb, WP + 3 * 110592, nbr, H2b, SM3, SM4);
  k_apply_res_bf<<<3750, 256, 0, stream>>>(H2b, SM4, Xb);

  // final 64->1 conv + bias: D = X.WF^T then gather-sum
  k_dfin<<<NROW / 64, 256, 0, stream>>>(Xb, wfin, D);
  k_gfin<<<NROW / 256, 256, 0, stream>>>(D, nbr, bfin, (float*)d_out);
}